// Round 18
// baseline (168.471 us; speedup 1.0000x reference)
//
#include <hip/hip_runtime.h>
#include <hip/hip_fp16.h>

#define NN 50000
#define NE 800000
#define FN 128
#define HH 256      // HEADS*HID
#define HID 64
#define NBKT 196    // 256-node buckets
#define CHUNK 4000  // edges per bin block; 200*4000 == NE
#define REGCAP 8192 // per-bucket region capacity (avg 4096, max ~4350)

typedef _Float16 f16x8 __attribute__((ext_vector_type(8)));
typedef float f32x4 __attribute__((ext_vector_type(4)));

__device__ __forceinline__ float lrelu(float v){ return v >= 0.f ? v : 0.2f * v; }
__device__ __forceinline__ float elu_(float v){ return v > 0.f ? v : expm1f(v); }

__device__ __forceinline__ void unp4(const float2 r, float& f0, float& f1, float& f2, float& f3){
  const __half2* hp = (const __half2*)&r;
  float2 a = __half22float2(hp[0]);
  float2 b = __half22float2(hp[1]);
  f0 = a.x; f1 = a.y; f2 = b.x; f3 = b.y;
}

// ---------- merged: weight prep (W1,W2,Wh) + task encoder + binCnt zero ----------
__global__ void k_misc(const float* __restrict__ W2, const float* __restrict__ W1,
                       __half* __restrict__ Bp, __half* __restrict__ Bp1, __half* __restrict__ Bwh,
                       const float* __restrict__ task, const float* __restrict__ W1t,
                       const float* __restrict__ b1t, const float* __restrict__ W2t,
                       const float* __restrict__ b2t, const float* __restrict__ clW1,
                       const float* __restrict__ clb1, float* __restrict__ tWb,
                       int* __restrict__ binCnt){
  int bid = blockIdx.x, t = threadIdx.x;
  if (bid < 26){                         // prep: 26 blocks cover f<6656
    int f = bid * 256 + t;
    if (f < 2048){
      int lane = f & 63;
      int ct = (f >> 6) & 3, kt = f >> 8;
      int kbase = kt * 32 + (lane >> 4) * 8;
      int col = ct * 16 + (lane & 15);
#pragma unroll
      for (int i = 0; i < 8; ++i)
        Bp[(size_t)f * 8 + i] = (__half)W2[(kbase + i) * HID + col];
    } else if (f < 6144){
      int g = f - 2048;
      int lane = g & 63;
      int ct = (g >> 6) & 15, kt = g >> 10;
      int kbase = kt * 32 + (lane >> 4) * 8;
      int col = ct * 16 + (lane & 15);
#pragma unroll
      for (int i = 0; i < 8; ++i)
        Bp1[(size_t)g * 8 + i] = (__half)W1[(kbase + i) * HH + col];
    } else {
      int g = f - 6144;                  // (kt*4+ct)*64+lane, kt<2, ct<4
      int lane = g & 63;
      int ct = (g >> 6) & 3, kt = g >> 8;
      int kbase = kt * 32 + (lane >> 4) * 8;
      int col = ct * 16 + (lane & 15);
#pragma unroll
      for (int i = 0; i < 8; ++i)
        Bwh[(size_t)g * 8 + i] = (__half)clW1[(kbase + i) * HID + col];
    }
  } else {                               // task block + binCnt zero
    binCnt[t] = 0;
    __shared__ float t1[16][64];
    __shared__ float t2[16][64];
    for (int idx = t; idx < 1024; idx += 256){
      int b = idx >> 6, c = idx & 63;
      float acc = b1t[c];
      for (int k = 0; k < 128; ++k) acc = fmaf(task[b*128 + k], W1t[k*64 + c], acc);
      t1[b][c] = fmaxf(acc, 0.f);
    }
    __syncthreads();
    for (int idx = t; idx < 1024; idx += 256){
      int b = idx >> 6, c = idx & 63;
      float acc = b2t[c];
      for (int k = 0; k < 64; ++k) acc = fmaf(t1[b][k], W2t[k*64 + c], acc);
      t2[b][c] = acc;
    }
    __syncthreads();
    for (int idx = t; idx < 1024; idx += 256){
      int b = idx >> 6, c = idx & 63;
      float acc = clb1[c];
      for (int k = 0; k < 64; ++k) acc = fmaf(t2[b][k], clW1[(64 + k)*64 + c], acc);
      tWb[idx] = acc;
    }
  }
}

// ---------- merged: LDS-binned edge partition (de-staged) + (h1 = x @ W1 MFMA) ----------
// packed: src(16b) | dlocal(8b)<<16 | bucket(8b)<<24
__global__ void k_binGemm(const int* __restrict__ ei, int* __restrict__ binCnt,
                          unsigned* __restrict__ pr,
                          const float* __restrict__ x, const __half* __restrict__ Bp1,
                          const float* __restrict__ as1, const float* __restrict__ ad1,
                          __half* __restrict__ h1h, float* __restrict__ als, float* __restrict__ ald){
  __shared__ int hist[NBKT];
  __shared__ int gpos[NBKT];
  __shared__ int cnt[NBKT];
  int bid = blockIdx.x, t = threadIdx.x;
  if (bid < 200){                        // bin: 200*4000 == NE
    int e_base = bid * CHUNK;
    if (t < NBKT){ hist[t] = 0; cnt[t] = 0; }
    __syncthreads();
    for (int i = t; i < CHUNK; i += 256)
      atomicAdd(&hist[ei[NE + e_base + i] >> 8], 1);
    __syncthreads();
    if (t < NBKT){
      int v = hist[t];
      gpos[t] = (v > 0) ? atomicAdd(&binCnt[t], v) : 0;
    }
    __syncthreads();
    for (int i = t; i < CHUNK; i += 256){
      int e = e_base + i;
      int s = ei[e], d = ei[NE + e];
      int bb = d >> 8;
      int r = atomicAdd(&cnt[bb], 1);
      pr[(size_t)bb * REGCAP + gpos[bb] + r] =
        (unsigned)s | ((unsigned)(d & 255) << 16) | ((unsigned)bb << 24);
    }
    return;
  }
  // gemm1m part
  int blk = bid - 200;
  int wv = t >> 6, lane = t & 63;
  int n0 = blk * 64 + wv * 16;           // 16 rows per wave
  int arow = n0 + (lane & 15);
  if (arow > NN - 1) arow = NN - 1;      // clamp for loads; stores guarded
  const float* xbase = x + (size_t)arow * FN + (lane >> 4) * 8;
  const f16x8* bbase = (const f16x8*)Bp1 + lane;   // + (kt*16+ct)*64

  f32x4 acc[16];
#pragma unroll
  for (int ct = 0; ct < 16; ++ct) acc[ct] = (f32x4){0.f,0.f,0.f,0.f};

#pragma unroll
  for (int kt = 0; kt < 4; ++kt){
    float4 xa = *(const float4*)(xbase + kt * 32);
    float4 xb = *(const float4*)(xbase + kt * 32 + 4);
    f16x8 a;
    a[0] = (_Float16)xa.x; a[1] = (_Float16)xa.y; a[2] = (_Float16)xa.z; a[3] = (_Float16)xa.w;
    a[4] = (_Float16)xb.x; a[5] = (_Float16)xb.y; a[6] = (_Float16)xb.z; a[7] = (_Float16)xb.w;
#pragma unroll
    for (int ct = 0; ct < 16; ++ct)
      acc[ct] = __builtin_amdgcn_mfma_f32_16x16x32_f16(a, bbase[(kt*16 + ct) * 64], acc[ct], 0, 0, 0);
  }

  // C/D mapping: col = ct*16 + (lane&15), row = (lane>>4)*4 + i
  int c4 = lane & 15, g4 = lane >> 4;
#pragma unroll
  for (int ct = 0; ct < 16; ++ct){
#pragma unroll
    for (int i = 0; i < 4; ++i){
      int n = n0 + g4 * 4 + i;
      if (n < NN) h1h[(size_t)n * HH + ct * 16 + c4] = (__half)acc[ct][i];
    }
  }
#pragma unroll
  for (int h = 0; h < 4; ++h){
    float sa0 = as1[(h*4+0)*16 + c4], sa1 = as1[(h*4+1)*16 + c4];
    float sa2 = as1[(h*4+2)*16 + c4], sa3 = as1[(h*4+3)*16 + c4];
    float da0 = ad1[(h*4+0)*16 + c4], da1 = ad1[(h*4+1)*16 + c4];
    float da2 = ad1[(h*4+2)*16 + c4], da3 = ad1[(h*4+3)*16 + c4];
#pragma unroll
    for (int i = 0; i < 4; ++i){
      float vs = acc[h*4+0][i]*sa0 + acc[h*4+1][i]*sa1 + acc[h*4+2][i]*sa2 + acc[h*4+3][i]*sa3;
      float vd = acc[h*4+0][i]*da0 + acc[h*4+1][i]*da1 + acc[h*4+2][i]*da2 + acc[h*4+3][i]*da3;
#pragma unroll
      for (int off = 1; off < 16; off <<= 1){
        vs += __shfl_xor(vs, off);
        vd += __shfl_xor(vd, off);
      }
      if (c4 == 0){
        int n = n0 + g4 * 4 + i;
        if (n < NN){ als[n*4 + h] = vs; ald[n*4 + h] = vd; }
      }
    }
  }
}

// ---------- rs + csr from regions: block b owns bucket b (nodes [256b,256b+256)) ----------
__global__ void k_rsplace(const int* __restrict__ binCnt, const unsigned* __restrict__ pr,
                          int* __restrict__ rs, int* __restrict__ csr){
  __shared__ int bbase[256];
  __shared__ int hist[256];
  __shared__ int lp[256];
  __shared__ int wsA[4];
  __shared__ int wsB[4];
  int b = blockIdx.x, t = threadIdx.x;
  int lane = t & 63, wv = t >> 6;
  {
    int v = (t < NBKT) ? binCnt[t] : 0;
    int iv = v;
#pragma unroll
    for (int off = 1; off < 64; off <<= 1){
      int u = __shfl_up(iv, off);
      if (lane >= off) iv += u;
    }
    if (lane == 63) wsA[wv] = iv;
    __syncthreads();
    int add = 0;
    for (int w = 0; w < wv; ++w) add += wsA[w];
    bbase[t] = iv + add - v;
    hist[t] = 0;
  }
  __syncthreads();
  int myBase = bbase[b];
  int myCnt  = binCnt[b];
  const unsigned* reg = pr + (size_t)b * REGCAP;
  for (int i = t; i < myCnt; i += 256)
    atomicAdd(&hist[(reg[i] >> 16) & 255], 1);
  __syncthreads();
  int excl;
  {
    int v = hist[t];
    int iv = v;
#pragma unroll
    for (int off = 1; off < 64; off <<= 1){
      int u = __shfl_up(iv, off);
      if (lane >= off) iv += u;
    }
    if (lane == 63) wsB[wv] = iv;
    __syncthreads();
    int add = 0;
    for (int w = 0; w < wv; ++w) add += wsB[w];
    excl = myBase + iv + add - v;
    lp[t] = excl;
  }
  int idx = b * 256 + t;
  if (idx < NN) rs[idx] = excl;
  if (b == 0 && t == 0) rs[NN] = NE;
  __syncthreads();
  for (int i = t; i < myCnt; i += 256){
    unsigned p = reg[i];
    int pos = atomicAdd(&lp[(p >> 16) & 255], 1);
    csr[pos] = (int)(p & 0xFFFFu);
  }
}

// ---------- fused: layer-1 weights+gather+ELU (LDS) -> g1@W2 MFMA -> h2 + alpha2 ----------
#define GSTRIDE 264   // halfs per g1 row in LDS (528 B) -> ~2-way bank aliasing
__global__ void k_agg1f2(const int* __restrict__ rs, const int* __restrict__ csr,
                         const __half* __restrict__ h1h, const float* __restrict__ als,
                         const float* __restrict__ ald, const float* __restrict__ b1,
                         const __half* __restrict__ Bp, const float* __restrict__ as2,
                         const float* __restrict__ ad2, __half* __restrict__ h2h,
                         float* __restrict__ als2, float* __restrict__ ald2){
  __shared__ __half g_lds[16 * GSTRIDE];   // 8.25 KB
  __shared__ float vsq[16][4];
  __shared__ float vdq[16][4];
  int t = threadIdx.x, wv = t >> 6, lane = t & 63;
  int head = lane >> 4, q = lane & 15;
  int hb = lane & 48;
  int nblk = blockIdx.x * 16;

#pragma unroll 1
  for (int j = 0; j < 4; ++j){
    int nl = wv * 4 + j;
    int n = nblk + nl;                     // 3125*16 == NN exactly
    int e0 = rs[n], e1 = rs[n + 1];
    int deg = e1 - e0;
    float adh = ald[n*4 + head];

    float w0r = 0.f, w1r = 0.f, w2r = 0.f, w3r = 0.f;
    int   s0r = 0,   s1r = 0,   s2r = 0,   s3r = 0;
    float den = 0.f;
    if (q      < deg){ s0r = csr[e0 + q];      w0r = expf(lrelu(als[s0r*4+head] + adh)); den += w0r; }
    if (q + 16 < deg){ s1r = csr[e0 + 16 + q]; w1r = expf(lrelu(als[s1r*4+head] + adh)); den += w1r; }
    if (q + 32 < deg){ s2r = csr[e0 + 32 + q]; w2r = expf(lrelu(als[s2r*4+head] + adh)); den += w2r; }
    if (q + 48 < deg){ s3r = csr[e0 + 48 + q]; w3r = expf(lrelu(als[s3r*4+head] + adh)); den += w3r; }
    for (int e = e0 + 64 + q; e < e1; e += 16) den += expf(lrelu(als[csr[e]*4+head] + adh));
    den += __shfl_xor(den, 1); den += __shfl_xor(den, 2);
    den += __shfl_xor(den, 4); den += __shfl_xor(den, 8);
    float selfw = expf(lrelu(als[n*4+head] + adh));
    float inv = 1.f / (den + selfw + 1e-16f);
    float wself = selfw * inv;

    float a0, a1, a2, a3;
    { float2 r = *(const float2*)(h1h + (size_t)n * HH + lane * 4);
      float f0,f1,f2,f3; unp4(r, f0,f1,f2,f3);
      a0 = wself*f0; a1 = wself*f1; a2 = wself*f2; a3 = wself*f3; }

    int cnt = deg < 64 ? deg : 64;
    auto pass = [&](float wp, int sp, int off){
      int lim = cnt - off; if (lim <= 0) return; if (lim > 16) lim = 16;
      for (int q2 = 0; q2 < lim; q2 += 4){          // wave-uniform trip count
        int j1 = q2 + 1, j2 = q2 + 2, j3 = q2 + 3;
        float m1 = (j1 < lim) ? inv : 0.f; if (j1 >= lim) j1 = q2;
        float m2 = (j2 < lim) ? inv : 0.f; if (j2 >= lim) j2 = q2;
        float m3 = (j3 < lim) ? inv : 0.f; if (j3 >= lim) j3 = q2;
        float wa = inv * __shfl(wp, hb + q2); int sa = __shfl(sp, hb + q2);
        float wb = m1  * __shfl(wp, hb + j1); int sb = __shfl(sp, hb + j1);
        float wc = m2  * __shfl(wp, hb + j2); int sc = __shfl(sp, hb + j2);
        float wd = m3  * __shfl(wp, hb + j3); int sd = __shfl(sp, hb + j3);
        float2 ra = *(const float2*)(h1h + (size_t)sa * HH + lane * 4);
        float2 rb = *(const float2*)(h1h + (size_t)sb * HH + lane * 4);
        float2 rc = *(const float2*)(h1h + (size_t)sc * HH + lane * 4);
        float2 rd = *(const float2*)(h1h + (size_t)sd * HH + lane * 4);
        float f0,f1,f2,f3;
        unp4(ra, f0,f1,f2,f3); a0=fmaf(wa,f0,a0); a1=fmaf(wa,f1,a1); a2=fmaf(wa,f2,a2); a3=fmaf(wa,f3,a3);
        unp4(rb, f0,f1,f2,f3); a0=fmaf(wb,f0,a0); a1=fmaf(wb,f1,a1); a2=fmaf(wb,f2,a2); a3=fmaf(wb,f3,a3);
        unp4(rc, f0,f1,f2,f3); a0=fmaf(wc,f0,a0); a1=fmaf(wc,f1,a1); a2=fmaf(wc,f2,a2); a3=fmaf(wc,f3,a3);
        unp4(rd, f0,f1,f2,f3); a0=fmaf(wd,f0,a0); a1=fmaf(wd,f1,a1); a2=fmaf(wd,f2,a2); a3=fmaf(wd,f3,a3);
      }
    };
    pass(w0r, s0r, 0); pass(w1r, s1r, 16); pass(w2r, s2r, 32); pass(w3r, s3r, 48);
    // rare tail: deg > 64, recompute weights directly (uniform loop)
    for (int e = e0 + 64; e < e1; ++e){
      int s = csr[e];
      float w = inv * expf(lrelu(als[s*4+head] + adh));
      float2 r = *(const float2*)(h1h + (size_t)s * HH + lane * 4);
      float f0,f1,f2,f3; unp4(r, f0,f1,f2,f3);
      a0=fmaf(w,f0,a0); a1=fmaf(w,f1,a1); a2=fmaf(w,f2,a2); a3=fmaf(w,f3,a3);
    }

    float4 b4 = *(const float4*)(b1 + lane * 4);
    __half2 p0 = __floats2half2_rn(elu_(a0 + b4.x), elu_(a1 + b4.y));
    __half2 p1 = __floats2half2_rn(elu_(a2 + b4.z), elu_(a3 + b4.w));
    float2 outv; ((__half2*)&outv)[0] = p0; ((__half2*)&outv)[1] = p1;
    *(float2*)(g_lds + nl * GSTRIDE + lane * 4) = outv;
  }
  __syncthreads();

  // h2 quadrant = g1(16 rows) @ W2 cols [wv*16, wv*16+16), K=256
  const _Float16* abase = (const _Float16*)g_lds + (lane & 15) * GSTRIDE + (lane >> 4) * 8;
  const f16x8* bbase = (const f16x8*)Bp + lane;   // + (kt*4+ct)*64, ct = wv

  f32x4 acc = {0.f,0.f,0.f,0.f};
#pragma unroll
  for (int kt = 0; kt < 8; ++kt){
    f16x8 a = *(const f16x8*)(abase + kt * 32);
    acc = __builtin_amdgcn_mfma_f32_16x16x32_f16(a, bbase[(kt*4 + wv) * 64], acc, 0, 0, 0);
  }
  // C layout: row = (lane>>4)*4 + i (node_local), col = wv*16 + (lane&15)
  int c4 = lane & 15, g4 = lane >> 4;
  int col = wv * 16 + c4;
  float as2v = as2[col], ad2v = ad2[col];
#pragma unroll
  for (int i = 0; i < 4; ++i){
    int nl = g4 * 4 + i;
    h2h[(size_t)(nblk + nl) * HID + col] = (__half)acc[i];
    // alpha2 partial for this wave's 16-col quadrant
    float vs = acc[i] * as2v, vd = acc[i] * ad2v;
    vs += __shfl_xor(vs, 1); vd += __shfl_xor(vd, 1);
    vs += __shfl_xor(vs, 2); vd += __shfl_xor(vd, 2);
    vs += __shfl_xor(vs, 4); vd += __shfl_xor(vd, 4);
    vs += __shfl_xor(vs, 8); vd += __shfl_xor(vd, 8);
    if (c4 == 0){ vsq[nl][wv] = vs; vdq[nl][wv] = vd; }
  }
  __syncthreads();
  if (t < 16){
    als2[nblk + t] = vsq[t][0] + vsq[t][1] + vsq[t][2] + vsq[t][3];
    ald2[nblk + t] = vdq[t][0] + vdq[t][1] + vdq[t][2] + vdq[t][3];
  }
}

// ---------- fused: layer-2 weights+gather+ELU (LDS) -> o@Wh MFMA -> scores ----------
#define OSTRIDE 72   // halfs; 144 B rows -> <=2-way LDS bank aliasing
__global__ void k_agg2f(const int* __restrict__ rs, const int* __restrict__ csr,
                        const __half* __restrict__ h2h, const float* __restrict__ als,
                        const float* __restrict__ ald, const float* __restrict__ b2,
                        const __half* __restrict__ Bwh, const float* __restrict__ tWb,
                        const float* __restrict__ w2, const float* __restrict__ b2s,
                        float* __restrict__ out){
  __shared__ __half o_lds[64 * OSTRIDE];
  __shared__ float tws[1024];
  __shared__ float w2s[64];
  int t = threadIdx.x, lane = t & 63, wv = t >> 6;
  for (int i = t; i < 1024; i += 256) tws[i] = tWb[i];
  if (t < 64) w2s[t] = w2[t];

  int q = lane & 15;
  int g = t >> 4;                      // group 0..15
  int n0b = blockIdx.x * 64;
  int gb = lane & 48;
#pragma unroll 1
  for (int j = 0; j < 4; ++j){
    int nl = g * 4 + j;                // node_local 0..63
    int n = n0b + nl;
    int nc = (n < NN) ? n : NN - 1;
    int e0 = rs[nc], e1 = rs[nc + 1];
    int deg = e1 - e0;
    float adn = ald[nc];

    float w0r = 0.f, w1r = 0.f, w2r = 0.f, w3r = 0.f;
    int   s0r = 0,   s1r = 0,   s2r = 0,   s3r = 0;
    float den = 0.f;
    if (q      < deg){ s0r = csr[e0 + q];      w0r = expf(lrelu(als[s0r] + adn)); den += w0r; }
    if (q + 16 < deg){ s1r = csr[e0 + 16 + q]; w1r = expf(lrelu(als[s1r] + adn)); den += w1r; }
    if (q + 32 < deg){ s2r = csr[e0 + 32 + q]; w2r = expf(lrelu(als[s2r] + adn)); den += w2r; }
    if (q + 48 < deg){ s3r = csr[e0 + 48 + q]; w3r = expf(lrelu(als[s3r] + adn)); den += w3r; }
    for (int e = e0 + 64 + q; e < e1; e += 16) den += expf(lrelu(als[csr[e]] + adn));
    den += __shfl_xor(den, 1); den += __shfl_xor(den, 2);
    den += __shfl_xor(den, 4); den += __shfl_xor(den, 8);
    float selfw = expf(lrelu(als[nc] + adn));
    float inv = 1.f / (den + selfw + 1e-16f);
    float wself = selfw * inv;

    float a0, a1, a2, a3;
    { float2 r = *(const float2*)(h2h + (size_t)nc * HID + q * 4);
      float f0,f1,f2,f3; unp4(r, f0,f1,f2,f3);
      a0 = wself*f0; a1 = wself*f1; a2 = wself*f2; a3 = wself*f3; }

    int dmax = deg;
    dmax = max(dmax, __shfl_xor(dmax, 16));
    dmax = max(dmax, __shfl_xor(dmax, 32));
    int cnt = dmax < 64 ? dmax : 64;
    auto pass = [&](float wp, int sp, int off){
      int lim = cnt - off; if (lim <= 0) return; if (lim > 16) lim = 16;
      for (int jj = 0; jj < lim; jj += 4){
        int j1 = jj + 1, j2 = jj + 2, j3 = jj + 3;
        float m1 = (j1 < lim) ? inv : 0.f; if (j1 >= lim) j1 = jj;
        float m2 = (j2 < lim) ? inv : 0.f; if (j2 >= lim) j2 = jj;
        float m3 = (j3 < lim) ? inv : 0.f; if (j3 >= lim) j3 = jj;
        float wa = inv * __shfl(wp, gb + jj); int sa = __shfl(sp, gb + jj);
        float wb = m1  * __shfl(wp, gb + j1); int sb = __shfl(sp, gb + j1);
        float wc = m2  * __shfl(wp, gb + j2); int sc = __shfl(sp, gb + j2);
        float wd = m3  * __shfl(wp, gb + j3); int sd = __shfl(sp, gb + j3);
        float2 ra = *(const float2*)(h2h + (size_t)sa * HID + q * 4);
        float2 rb = *(const float2*)(h2h + (size_t)sb * HID + q * 4);
        float2 rc = *(const float2*)(h2h + (size_t)sc * HID + q * 4);
        float2 rd = *(const float2*)(h2h + (size_t)sd * HID + q * 4);
        float f0,f1,f2,f3;
        unp4(ra, f0,f1,f2,f3); a0=fmaf(wa,f0,a0); a1=fmaf(wa,f1,a1); a2=fmaf(wa,f2,a2); a3=fmaf(wa,f3,a3);
        unp4(rb, f0,f1,f2,f3); a0=fmaf(wb,f0,a0); a1=fmaf(wb,f1,a1); a2=fmaf(wb,f2,a2); a3=fmaf(wb,f3,a3);
        unp4(rc, f0,f1,f2,f3); a0=fmaf(wc,f0,a0); a1=fmaf(wc,f1,a1); a2=fmaf(wc,f2,a2); a3=fmaf(wc,f3,a3);
        unp4(rd, f0,f1,f2,f3); a0=fmaf(wd,f0,a0); a1=fmaf(wd,f1,a1); a2=fmaf(wd,f2,a2); a3=fmaf(wd,f3,a3);
      }
    };
    pass(w0r, s0r, 0); pass(w1r, s1r, 16); pass(w2r, s2r, 32); pass(w3r, s3r, 48);
    for (int e = e0 + 64; e < e1; ++e){
      int s = csr[e];
      float w = inv * expf(lrelu(als[s] + adn));
      float2 r = *(const float2*)(h2h + (size_t)s * HID + q * 4);
      float f0,f1,f2,f3; unp4(r, f0,f1,f2,f3);
      a0=fmaf(w,f0,a0); a1=fmaf(w,f1,a1); a2=fmaf(w,f2,a2); a3=fmaf(w,f3,a3);
    }

    float4 b4 = *(const float4*)(b2 + q * 4);
    __half2 p0 = __floats2half2_rn(elu_(a0 + b4.x), elu_(a1 + b4.y));
    __half2 p1 = __floats2half2_rn(elu_(a2 + b4.z), elu_(a3 + b4.w));
    float2 outv; ((__half2*)&outv)[0] = p0; ((__half2*)&outv)[1] = p1;
    *(float2*)(o_lds + nl * OSTRIDE + q * 4) = outv;
  }
  __syncthreads();

  // hW MFMA + fused scores (wave wv handles nodes n0b + wv*16 .. +15)
  const _Float16* obase = (const _Float16*)o_lds + (wv * 16 + (lane & 15)) * OSTRIDE + (lane >> 4) * 8;
  const f16x8* bbase = (const f16x8*)Bwh + lane;   // + (kt*4+ct)*64

  f32x4 acc[4];
#pragma unroll
  for (int ct = 0; ct < 4; ++ct) acc[ct] = (f32x4){0.f,0.f,0.f,0.f};
#pragma unroll
  for (int kt = 0; kt < 2; ++kt){
    f16x8 a = *(const f16x8*)(obase + kt * 32);
#pragma unroll
    for (int ct = 0; ct < 4; ++ct)
      acc[ct] = __builtin_amdgcn_mfma_f32_16x16x32_f16(a, bbase[(kt*4 + ct) * 64], acc[ct], 0, 0, 0);
  }
  int c4 = lane & 15, g4 = lane >> 4;
  float wv0 = w2s[c4], wv1 = w2s[16 + c4], wv2 = w2s[32 + c4], wv3 = w2s[48 + c4];
  float bias = b2s[0];
#pragma unroll
  for (int i = 0; i < 4; ++i){
    int n = n0b + wv * 16 + g4 * 4 + i;
    float v[16];
#pragma unroll
    for (int b = 0; b < 16; ++b){
      const float* twb = tws + b * 64;
      v[b] = fmaxf(acc[0][i] + twb[c4], 0.f)      * wv0
           + fmaxf(acc[1][i] + twb[16 + c4], 0.f) * wv1
           + fmaxf(acc[2][i] + twb[32 + c4], 0.f) * wv2
           + fmaxf(acc[3][i] + twb[48 + c4], 0.f) * wv3;
    }
    bool h3 = (lane & 8) != 0;
    float u[8];
#pragma unroll
    for (int jj = 0; jj < 8; ++jj){
      float keep = h3 ? v[jj+8] : v[jj];
      float send = h3 ? v[jj]   : v[jj+8];
      u[jj] = keep + __shfl_xor(send, 8);
    }
    bool h2b = (lane & 4) != 0;
    float p[4];
#pragma unroll
    for (int jj = 0; jj < 4; ++jj){
      float keep = h2b ? u[jj+4] : u[jj];
      float send = h2b ? u[jj]   : u[jj+4];
      p[jj] = keep + __shfl_xor(send, 4);
    }
    bool h1b = (lane & 2) != 0;
    float qq[2];
#pragma unroll
    for (int jj = 0; jj < 2; ++jj){
      float keep = h1b ? p[jj+2] : p[jj];
      float send = h1b ? p[jj]   : p[jj+2];
      qq[jj] = keep + __shfl_xor(send, 2);
    }
    bool h0 = (lane & 1) != 0;
    float keep = h0 ? qq[1] : qq[0];
    float send = h0 ? qq[0] : qq[1];
    float z = keep + __shfl_xor(send, 1);
    if (n < NN) out[(size_t)c4 * NN + n] = z + bias;
  }
}

extern "C" void kernel_launch(void* const* d_in, const int* in_sizes, int n_in,
                              void* d_out, int out_size, void* d_ws, size_t ws_size,
                              hipStream_t stream){
  const float* x    = (const float*)d_in[0];
  const int*   ei   = (const int*)  d_in[1];
  const float* task = (const float*)d_in[2];
  const float* W1   = (const float*)d_in[3];
  const float* as1  = (const float*)d_in[4];
  const float* ad1  = (const float*)d_in[5];
  const float* b1   = (const float*)d_in[6];
  const float* W2   = (const float*)d_in[7];
  const float* as2  = (const float*)d_in[8];
  const float* ad2  = (const float*)d_in[9];
  const float* b2   = (const float*)d_in[10];
  const float* teW1 = (const float*)d_in[11];
  const float* teb1 = (const float*)d_in[12];
  const float* teW2 = (const float*)d_in[13];
  const float* teb2 = (const float*)d_in[14];
  const float* clW1 = (const float*)d_in[15];
  const float* clb1 = (const float*)d_in[16];
  const float* clW2 = (const float*)d_in[17];
  const float* clb2 = (const float*)d_in[18];
  float* out = (float*)d_out;
  float* ws  = (float*)d_ws;

  // workspace layout (float-sized slots)
  __half* h1h  = (__half*)ws;                    // 12.8M halfs -> 6.4M floats
  float* als1  = ws + 6400000;                   // 200,000
  float* ald1  = als1 + 200000;                  // 200,000
  __half* h2h  = (__half*)(ald1 + 200000);       // 3.2M halfs -> 1.6M floats
  float* als2  = ald1 + 200000 + 1600000;        // 50,000
  float* ald2  = als2 + 50000;                   // 50,000
  float* tWb   = ald2 + 50000;                   // 1,024
  int*   rs    = (int*)(tWb + 1024);             // 50,001 (+pad)
  int*   csr   = rs + 50004;                     // 800,000
  int*   binCnt= csr + 800000;                   // 256
  __half* Bp   = (__half*)(binCnt + 256);        // 16,384 halfs (MFMA-ordered W2)
  __half* Bp1  = Bp + 16384;                     // 32,768 halfs (MFMA-ordered W1)
  __half* Bwh  = Bp1 + 32768;                    // 4,096 halfs (MFMA-ordered Wh)
  unsigned* pr = (unsigned*)(Bwh + 4096);        // 196*8192 packed pairs (6.4 MB)

  // weight prep + task encoder + binCnt zero (27 blocks)
  k_misc   <<<27, 256, 0, stream>>>(W2, W1, Bp, Bp1, Bwh,
                                    task, teW1, teb1, teW2, teb2, clW1, clb1, tWb, binCnt);
  // LDS-binned edge partition into regions + layer-1 GEMM (one launch)
  k_binGemm<<<200 + (NN + 63)/64, 256, 0, stream>>>(ei, binCnt, pr, x, Bp1,
                                                    as1, ad1, h1h, als1, ald1);
  // rs + csr from regions
  k_rsplace<<<NBKT, 256, 0, stream>>>(binCnt, pr, rs, csr);
  // layer 1 aggregate + layer-2 GEMM + alpha2 (fused; 3125*16 == NN)
  k_agg1f2 <<<3125, 256, 0, stream>>>(rs, csr, h1h, als1, ald1, b1,
                                      Bp, as2, ad2, h2h, als2, ald2);
  // layer 2 aggregate + hW MFMA + scores (fused)
  k_agg2f  <<<(NN + 63)/64, 256, 0, stream>>>(rs, csr, h2h, als2, ald2, b2,
                                              Bwh, tWb, clW2, clb2, out);
}

// Round 19
// 164.569 us; speedup vs baseline: 1.0237x; 1.0237x over previous
//
#include <hip/hip_runtime.h>
#include <hip/hip_fp16.h>

#define NN 50000
#define NE 800000
#define FN 128
#define HH 256      // HEADS*HID
#define HID 64
#define NBKT 196    // 256-node buckets
#define CHUNK 4000  // edges per bin block; 200*4000 == NE
#define REGCAP 8192 // per-bucket region capacity (avg 4096, max ~4350)

typedef _Float16 f16x8 __attribute__((ext_vector_type(8)));
typedef float f32x4 __attribute__((ext_vector_type(4)));

__device__ __forceinline__ float lrelu(float v){ return v >= 0.f ? v : 0.2f * v; }
__device__ __forceinline__ float elu_(float v){ return v > 0.f ? v : expm1f(v); }

__device__ __forceinline__ void unp4(const float2 r, float& f0, float& f1, float& f2, float& f3){
  const __half2* hp = (const __half2*)&r;
  float2 a = __half22float2(hp[0]);
  float2 b = __half22float2(hp[1]);
  f0 = a.x; f1 = a.y; f2 = b.x; f3 = b.y;
}

// ---------- merged: weight prep (W1,W2,Wh) + task encoder + binCnt zero ----------
__global__ void k_misc(const float* __restrict__ W2, const float* __restrict__ W1,
                       __half* __restrict__ Bp, __half* __restrict__ Bp1, __half* __restrict__ Bwh,
                       const float* __restrict__ task, const float* __restrict__ W1t,
                       const float* __restrict__ b1t, const float* __restrict__ W2t,
                       const float* __restrict__ b2t, const float* __restrict__ clW1,
                       const float* __restrict__ clb1, float* __restrict__ tWb,
                       int* __restrict__ binCnt){
  int bid = blockIdx.x, t = threadIdx.x;
  if (bid < 26){                         // prep: 26 blocks cover f<6656
    int f = bid * 256 + t;
    if (f < 2048){
      int lane = f & 63;
      int ct = (f >> 6) & 3, kt = f >> 8;
      int kbase = kt * 32 + (lane >> 4) * 8;
      int col = ct * 16 + (lane & 15);
#pragma unroll
      for (int i = 0; i < 8; ++i)
        Bp[(size_t)f * 8 + i] = (__half)W2[(kbase + i) * HID + col];
    } else if (f < 6144){
      int g = f - 2048;
      int lane = g & 63;
      int ct = (g >> 6) & 15, kt = g >> 10;
      int kbase = kt * 32 + (lane >> 4) * 8;
      int col = ct * 16 + (lane & 15);
#pragma unroll
      for (int i = 0; i < 8; ++i)
        Bp1[(size_t)g * 8 + i] = (__half)W1[(kbase + i) * HH + col];
    } else {
      int g = f - 6144;                  // (kt*4+ct)*64+lane, kt<2, ct<4
      int lane = g & 63;
      int ct = (g >> 6) & 3, kt = g >> 8;
      int kbase = kt * 32 + (lane >> 4) * 8;
      int col = ct * 16 + (lane & 15);
#pragma unroll
      for (int i = 0; i < 8; ++i)
        Bwh[(size_t)g * 8 + i] = (__half)clW1[(kbase + i) * HID + col];
    }
  } else {                               // task block + binCnt zero
    binCnt[t] = 0;
    __shared__ float t1[16][64];
    __shared__ float t2[16][64];
    for (int idx = t; idx < 1024; idx += 256){
      int b = idx >> 6, c = idx & 63;
      float acc = b1t[c];
      for (int k = 0; k < 128; ++k) acc = fmaf(task[b*128 + k], W1t[k*64 + c], acc);
      t1[b][c] = fmaxf(acc, 0.f);
    }
    __syncthreads();
    for (int idx = t; idx < 1024; idx += 256){
      int b = idx >> 6, c = idx & 63;
      float acc = b2t[c];
      for (int k = 0; k < 64; ++k) acc = fmaf(t1[b][k], W2t[k*64 + c], acc);
      t2[b][c] = acc;
    }
    __syncthreads();
    for (int idx = t; idx < 1024; idx += 256){
      int b = idx >> 6, c = idx & 63;
      float acc = clb1[c];
      for (int k = 0; k < 64; ++k) acc = fmaf(t2[b][k], clW1[(64 + k)*64 + c], acc);
      tWb[idx] = acc;
    }
  }
}

// ---------- merged: LDS-binned edge partition into regions + (h1 = x @ W1 MFMA) ----------
// packed: src(16b) | dlocal(8b)<<16 | bucket(8b)<<24
__global__ void k_binGemm(const int* __restrict__ ei, int* __restrict__ binCnt,
                          unsigned* __restrict__ pr,
                          const float* __restrict__ x, const __half* __restrict__ Bp1,
                          const float* __restrict__ as1, const float* __restrict__ ad1,
                          __half* __restrict__ h1h, float* __restrict__ als, float* __restrict__ ald){
  __shared__ int hist[NBKT];
  __shared__ int lstart[NBKT];
  __shared__ int gpos[NBKT];
  __shared__ int cnt[NBKT];
  __shared__ unsigned stage[CHUNK];      // 16 KB
  int bid = blockIdx.x, t = threadIdx.x;
  if (bid < 200){                        // bin: 200*4000 == NE
    int e_base = bid * CHUNK;
    if (t < NBKT){ hist[t] = 0; cnt[t] = 0; }
    __syncthreads();
    for (int i = t; i < CHUNK; i += 256)
      atomicAdd(&hist[ei[NE + e_base + i] >> 8], 1);
    __syncthreads();
    {
      int lane = t & 63, wvi = t >> 6;
      int v = (t < NBKT) ? hist[t] : 0;
      int iv = v;
#pragma unroll
      for (int off = 1; off < 64; off <<= 1){
        int u = __shfl_up(iv, off);
        if (lane >= off) iv += u;
      }
      __shared__ int wsum[4];
      if (lane == 63) wsum[wvi] = iv;
      __syncthreads();
      int add = 0;
      for (int w = 0; w < wvi; ++w) add += wsum[w];
      iv += add;
      if (t < NBKT){
        lstart[t] = iv - v;
        gpos[t] = (v > 0) ? atomicAdd(&binCnt[t], v) : 0;
      }
    }
    __syncthreads();
    for (int i = t; i < CHUNK; i += 256){
      int e = e_base + i;
      int s = ei[e], d = ei[NE + e];
      int bb = d >> 8;
      int r = atomicAdd(&cnt[bb], 1);
      stage[lstart[bb] + r] = (unsigned)s | ((unsigned)(d & 255) << 16) | ((unsigned)bb << 24);
    }
    __syncthreads();
    for (int i = t; i < CHUNK; i += 256){
      unsigned p = stage[i];
      int bb = p >> 24;
      pr[(size_t)bb * REGCAP + gpos[bb] + (i - lstart[bb])] = p;
    }
    return;
  }
  // gemm1m part
  int blk = bid - 200;
  int wv = t >> 6, lane = t & 63;
  int n0 = blk * 64 + wv * 16;           // 16 rows per wave
  int arow = n0 + (lane & 15);
  if (arow > NN - 1) arow = NN - 1;      // clamp for loads; stores guarded
  const float* xbase = x + (size_t)arow * FN + (lane >> 4) * 8;
  const f16x8* bbase = (const f16x8*)Bp1 + lane;   // + (kt*16+ct)*64

  f32x4 acc[16];
#pragma unroll
  for (int ct = 0; ct < 16; ++ct) acc[ct] = (f32x4){0.f,0.f,0.f,0.f};

#pragma unroll
  for (int kt = 0; kt < 4; ++kt){
    float4 xa = *(const float4*)(xbase + kt * 32);
    float4 xb = *(const float4*)(xbase + kt * 32 + 4);
    f16x8 a;
    a[0] = (_Float16)xa.x; a[1] = (_Float16)xa.y; a[2] = (_Float16)xa.z; a[3] = (_Float16)xa.w;
    a[4] = (_Float16)xb.x; a[5] = (_Float16)xb.y; a[6] = (_Float16)xb.z; a[7] = (_Float16)xb.w;
#pragma unroll
    for (int ct = 0; ct < 16; ++ct)
      acc[ct] = __builtin_amdgcn_mfma_f32_16x16x32_f16(a, bbase[(kt*16 + ct) * 64], acc[ct], 0, 0, 0);
  }

  // C/D mapping: col = ct*16 + (lane&15), row = (lane>>4)*4 + i
  int c4 = lane & 15, g4 = lane >> 4;
#pragma unroll
  for (int ct = 0; ct < 16; ++ct){
#pragma unroll
    for (int i = 0; i < 4; ++i){
      int n = n0 + g4 * 4 + i;
      if (n < NN) h1h[(size_t)n * HH + ct * 16 + c4] = (__half)acc[ct][i];
    }
  }
#pragma unroll
  for (int h = 0; h < 4; ++h){
    float sa0 = as1[(h*4+0)*16 + c4], sa1 = as1[(h*4+1)*16 + c4];
    float sa2 = as1[(h*4+2)*16 + c4], sa3 = as1[(h*4+3)*16 + c4];
    float da0 = ad1[(h*4+0)*16 + c4], da1 = ad1[(h*4+1)*16 + c4];
    float da2 = ad1[(h*4+2)*16 + c4], da3 = ad1[(h*4+3)*16 + c4];
#pragma unroll
    for (int i = 0; i < 4; ++i){
      float vs = acc[h*4+0][i]*sa0 + acc[h*4+1][i]*sa1 + acc[h*4+2][i]*sa2 + acc[h*4+3][i]*sa3;
      float vd = acc[h*4+0][i]*da0 + acc[h*4+1][i]*da1 + acc[h*4+2][i]*da2 + acc[h*4+3][i]*da3;
#pragma unroll
      for (int off = 1; off < 16; off <<= 1){
        vs += __shfl_xor(vs, off);
        vd += __shfl_xor(vd, off);
      }
      if (c4 == 0){
        int n = n0 + g4 * 4 + i;
        if (n < NN){ als[n*4 + h] = vs; ald[n*4 + h] = vd; }
      }
    }
  }
}

// ---------- rs + csr from regions: block b owns bucket b (nodes [256b,256b+256)) ----------
__global__ void k_rsplace(const int* __restrict__ binCnt, const unsigned* __restrict__ pr,
                          int* __restrict__ rs, int* __restrict__ csr){
  __shared__ int bbase[256];
  __shared__ int hist[256];
  __shared__ int lp[256];
  __shared__ int wsA[4];
  __shared__ int wsB[4];
  int b = blockIdx.x, t = threadIdx.x;
  int lane = t & 63, wv = t >> 6;
  {
    int v = (t < NBKT) ? binCnt[t] : 0;
    int iv = v;
#pragma unroll
    for (int off = 1; off < 64; off <<= 1){
      int u = __shfl_up(iv, off);
      if (lane >= off) iv += u;
    }
    if (lane == 63) wsA[wv] = iv;
    __syncthreads();
    int add = 0;
    for (int w = 0; w < wv; ++w) add += wsA[w];
    bbase[t] = iv + add - v;
    hist[t] = 0;
  }
  __syncthreads();
  int myBase = bbase[b];
  int myCnt  = binCnt[b];
  const unsigned* reg = pr + (size_t)b * REGCAP;
  for (int i = t; i < myCnt; i += 256)
    atomicAdd(&hist[(reg[i] >> 16) & 255], 1);
  __syncthreads();
  int excl;
  {
    int v = hist[t];
    int iv = v;
#pragma unroll
    for (int off = 1; off < 64; off <<= 1){
      int u = __shfl_up(iv, off);
      if (lane >= off) iv += u;
    }
    if (lane == 63) wsB[wv] = iv;
    __syncthreads();
    int add = 0;
    for (int w = 0; w < wv; ++w) add += wsB[w];
    excl = myBase + iv + add - v;
    lp[t] = excl;
  }
  int idx = b * 256 + t;
  if (idx < NN) rs[idx] = excl;
  if (b == 0 && t == 0) rs[NN] = NE;
  __syncthreads();
  for (int i = t; i < myCnt; i += 256){
    unsigned p = reg[i];
    int pos = atomicAdd(&lp[(p >> 16) & 255], 1);
    csr[pos] = (int)(p & 0xFFFFu);
  }
}

// ---------- fused: layer-1 weights+gather+ELU (LDS) -> g1@W2 MFMA -> h2 + alpha2 ----------
#define GSTRIDE 264   // halfs per g1 row in LDS (528 B) -> ~2-way bank aliasing
__global__ void k_agg1f2(const int* __restrict__ rs, const int* __restrict__ csr,
                         const __half* __restrict__ h1h, const float* __restrict__ als,
                         const float* __restrict__ ald, const float* __restrict__ b1,
                         const __half* __restrict__ Bp, const float* __restrict__ as2,
                         const float* __restrict__ ad2, __half* __restrict__ h2h,
                         float* __restrict__ als2, float* __restrict__ ald2){
  __shared__ __half g_lds[16 * GSTRIDE];   // 8.25 KB
  __shared__ float h2s[16][68];            // 4.25 KB
  int t = threadIdx.x, wv = t >> 6, lane = t & 63;
  int head = lane >> 4, q = lane & 15;
  int hb = lane & 48;
  int nblk = blockIdx.x * 16;

#pragma unroll 1
  for (int j = 0; j < 4; ++j){
    int nl = wv * 4 + j;
    int n = nblk + nl;                     // 3125*16 == NN exactly
    int e0 = rs[n], e1 = rs[n + 1];
    int deg = e1 - e0;
    float adh = ald[n*4 + head];

    float w0r = 0.f, w1r = 0.f, w2r = 0.f, w3r = 0.f;
    int   s0r = 0,   s1r = 0,   s2r = 0,   s3r = 0;
    float den = 0.f;
    if (q      < deg){ s0r = csr[e0 + q];      w0r = expf(lrelu(als[s0r*4+head] + adh)); den += w0r; }
    if (q + 16 < deg){ s1r = csr[e0 + 16 + q]; w1r = expf(lrelu(als[s1r*4+head] + adh)); den += w1r; }
    if (q + 32 < deg){ s2r = csr[e0 + 32 + q]; w2r = expf(lrelu(als[s2r*4+head] + adh)); den += w2r; }
    if (q + 48 < deg){ s3r = csr[e0 + 48 + q]; w3r = expf(lrelu(als[s3r*4+head] + adh)); den += w3r; }
    for (int e = e0 + 64 + q; e < e1; e += 16) den += expf(lrelu(als[csr[e]*4+head] + adh));
    den += __shfl_xor(den, 1); den += __shfl_xor(den, 2);
    den += __shfl_xor(den, 4); den += __shfl_xor(den, 8);
    float selfw = expf(lrelu(als[n*4+head] + adh));
    float inv = 1.f / (den + selfw + 1e-16f);
    float wself = selfw * inv;

    float a0, a1, a2, a3;
    { float2 r = *(const float2*)(h1h + (size_t)n * HH + lane * 4);
      float f0,f1,f2,f3; unp4(r, f0,f1,f2,f3);
      a0 = wself*f0; a1 = wself*f1; a2 = wself*f2; a3 = wself*f3; }

    int cnt = deg < 64 ? deg : 64;
    auto pass = [&](float wp, int sp, int off){
      int lim = cnt - off; if (lim <= 0) return; if (lim > 16) lim = 16;
      for (int q2 = 0; q2 < lim; q2 += 4){          // wave-uniform trip count
        int j1 = q2 + 1, j2 = q2 + 2, j3 = q2 + 3;
        float m1 = (j1 < lim) ? inv : 0.f; if (j1 >= lim) j1 = q2;
        float m2 = (j2 < lim) ? inv : 0.f; if (j2 >= lim) j2 = q2;
        float m3 = (j3 < lim) ? inv : 0.f; if (j3 >= lim) j3 = q2;
        float wa = inv * __shfl(wp, hb + q2); int sa = __shfl(sp, hb + q2);
        float wb = m1  * __shfl(wp, hb + j1); int sb = __shfl(sp, hb + j1);
        float wc = m2  * __shfl(wp, hb + j2); int sc = __shfl(sp, hb + j2);
        float wd = m3  * __shfl(wp, hb + j3); int sd = __shfl(sp, hb + j3);
        float2 ra = *(const float2*)(h1h + (size_t)sa * HH + lane * 4);
        float2 rb = *(const float2*)(h1h + (size_t)sb * HH + lane * 4);
        float2 rc = *(const float2*)(h1h + (size_t)sc * HH + lane * 4);
        float2 rd = *(const float2*)(h1h + (size_t)sd * HH + lane * 4);
        float f0,f1,f2,f3;
        unp4(ra, f0,f1,f2,f3); a0=fmaf(wa,f0,a0); a1=fmaf(wa,f1,a1); a2=fmaf(wa,f2,a2); a3=fmaf(wa,f3,a3);
        unp4(rb, f0,f1,f2,f3); a0=fmaf(wb,f0,a0); a1=fmaf(wb,f1,a1); a2=fmaf(wb,f2,a2); a3=fmaf(wb,f3,a3);
        unp4(rc, f0,f1,f2,f3); a0=fmaf(wc,f0,a0); a1=fmaf(wc,f1,a1); a2=fmaf(wc,f2,a2); a3=fmaf(wc,f3,a3);
        unp4(rd, f0,f1,f2,f3); a0=fmaf(wd,f0,a0); a1=fmaf(wd,f1,a1); a2=fmaf(wd,f2,a2); a3=fmaf(wd,f3,a3);
      }
    };
    pass(w0r, s0r, 0); pass(w1r, s1r, 16); pass(w2r, s2r, 32); pass(w3r, s3r, 48);
    // rare tail: deg > 64, recompute weights directly (uniform loop)
    for (int e = e0 + 64; e < e1; ++e){
      int s = csr[e];
      float w = inv * expf(lrelu(als[s*4+head] + adh));
      float2 r = *(const float2*)(h1h + (size_t)s * HH + lane * 4);
      float f0,f1,f2,f3; unp4(r, f0,f1,f2,f3);
      a0=fmaf(w,f0,a0); a1=fmaf(w,f1,a1); a2=fmaf(w,f2,a2); a3=fmaf(w,f3,a3);
    }

    float4 b4 = *(const float4*)(b1 + lane * 4);
    __half2 p0 = __floats2half2_rn(elu_(a0 + b4.x), elu_(a1 + b4.y));
    __half2 p1 = __floats2half2_rn(elu_(a2 + b4.z), elu_(a3 + b4.w));
    float2 outv; ((__half2*)&outv)[0] = p0; ((__half2*)&outv)[1] = p1;
    *(float2*)(g_lds + nl * GSTRIDE + lane * 4) = outv;
  }
  __syncthreads();

  // h2 quadrant = g1(16 rows) @ W2 cols [wv*16, wv*16+16), K=256
  const _Float16* abase = (const _Float16*)g_lds + (lane & 15) * GSTRIDE + (lane >> 4) * 8;
  const f16x8* bbase = (const f16x8*)Bp + lane;   // + (kt*4+ct)*64, ct = wv

  f32x4 acc = {0.f,0.f,0.f,0.f};
#pragma unroll
  for (int kt = 0; kt < 8; ++kt){
    f16x8 a = *(const f16x8*)(abase + kt * 32);
    acc = __builtin_amdgcn_mfma_f32_16x16x32_f16(a, bbase[(kt*4 + wv) * 64], acc, 0, 0, 0);
  }
  // C layout: row = (lane>>4)*4 + i (node_local), col = wv*16 + (lane&15)
  int c4 = lane & 15, g4 = lane >> 4;
  int col = wv * 16 + c4;
#pragma unroll
  for (int i = 0; i < 4; ++i){
    int nl = g4 * 4 + i;
    h2h[(size_t)(nblk + nl) * HID + col] = (__half)acc[i];
    h2s[nl][col] = acc[i];
  }
  __syncthreads();

  // alpha2: thread (nl2 = t>>4, l16 = t&15) sums cols l16*4..+3
  int nl2 = t >> 4, l16 = t & 15;
  float vs = 0.f, vd = 0.f;
#pragma unroll
  for (int k = 0; k < 4; ++k){
    int c2 = l16 * 4 + k;
    float hv = h2s[nl2][c2];
    vs = fmaf(hv, as2[c2], vs);
    vd = fmaf(hv, ad2[c2], vd);
  }
  vs += __shfl_xor(vs, 1); vd += __shfl_xor(vd, 1);
  vs += __shfl_xor(vs, 2); vd += __shfl_xor(vd, 2);
  vs += __shfl_xor(vs, 4); vd += __shfl_xor(vd, 4);
  vs += __shfl_xor(vs, 8); vd += __shfl_xor(vd, 8);
  if (l16 == 0){
    int n = nblk + nl2;
    als2[n] = vs; ald2[n] = vd;
  }
}

// ---------- fused: layer-2 weights+gather+ELU (LDS) -> o@Wh MFMA -> scores ----------
#define OSTRIDE 72   // halfs; 144 B rows -> <=2-way LDS bank aliasing
__global__ void k_agg2f(const int* __restrict__ rs, const int* __restrict__ csr,
                        const __half* __restrict__ h2h, const float* __restrict__ als,
                        const float* __restrict__ ald, const float* __restrict__ b2,
                        const __half* __restrict__ Bwh, const float* __restrict__ tWb,
                        const float* __restrict__ w2, const float* __restrict__ b2s,
                        float* __restrict__ out){
  __shared__ __half o_lds[64 * OSTRIDE];
  __shared__ float tws[1024];
  __shared__ float w2s[64];
  int t = threadIdx.x, lane = t & 63, wv = t >> 6;
  for (int i = t; i < 1024; i += 256) tws[i] = tWb[i];
  if (t < 64) w2s[t] = w2[t];

  int q = lane & 15;
  int g = t >> 4;                      // group 0..15
  int n0b = blockIdx.x * 64;
  int gb = lane & 48;
#pragma unroll 1
  for (int j = 0; j < 4; ++j){
    int nl = g * 4 + j;                // node_local 0..63
    int n = n0b + nl;
    int nc = (n < NN) ? n : NN - 1;
    int e0 = rs[nc], e1 = rs[nc + 1];
    int deg = e1 - e0;
    float adn = ald[nc];

    float w0r = 0.f, w1r = 0.f, w2r = 0.f, w3r = 0.f;
    int   s0r = 0,   s1r = 0,   s2r = 0,   s3r = 0;
    float den = 0.f;
    if (q      < deg){ s0r = csr[e0 + q];      w0r = expf(lrelu(als[s0r] + adn)); den += w0r; }
    if (q + 16 < deg){ s1r = csr[e0 + 16 + q]; w1r = expf(lrelu(als[s1r] + adn)); den += w1r; }
    if (q + 32 < deg){ s2r = csr[e0 + 32 + q]; w2r = expf(lrelu(als[s2r] + adn)); den += w2r; }
    if (q + 48 < deg){ s3r = csr[e0 + 48 + q]; w3r = expf(lrelu(als[s3r] + adn)); den += w3r; }
    for (int e = e0 + 64 + q; e < e1; e += 16) den += expf(lrelu(als[csr[e]] + adn));
    den += __shfl_xor(den, 1); den += __shfl_xor(den, 2);
    den += __shfl_xor(den, 4); den += __shfl_xor(den, 8);
    float selfw = expf(lrelu(als[nc] + adn));
    float inv = 1.f / (den + selfw + 1e-16f);
    float wself = selfw * inv;

    float a0, a1, a2, a3;
    { float2 r = *(const float2*)(h2h + (size_t)nc * HID + q * 4);
      float f0,f1,f2,f3; unp4(r, f0,f1,f2,f3);
      a0 = wself*f0; a1 = wself*f1; a2 = wself*f2; a3 = wself*f3; }

    int dmax = deg;
    dmax = max(dmax, __shfl_xor(dmax, 16));
    dmax = max(dmax, __shfl_xor(dmax, 32));
    int cnt = dmax < 64 ? dmax : 64;
    auto pass = [&](float wp, int sp, int off){
      int lim = cnt - off; if (lim <= 0) return; if (lim > 16) lim = 16;
      for (int jj = 0; jj < lim; jj += 4){
        int j1 = jj + 1, j2 = jj + 2, j3 = jj + 3;
        float m1 = (j1 < lim) ? inv : 0.f; if (j1 >= lim) j1 = jj;
        float m2 = (j2 < lim) ? inv : 0.f; if (j2 >= lim) j2 = jj;
        float m3 = (j3 < lim) ? inv : 0.f; if (j3 >= lim) j3 = jj;
        float wa = inv * __shfl(wp, gb + jj); int sa = __shfl(sp, gb + jj);
        float wb = m1  * __shfl(wp, gb + j1); int sb = __shfl(sp, gb + j1);
        float wc = m2  * __shfl(wp, gb + j2); int sc = __shfl(sp, gb + j2);
        float wd = m3  * __shfl(wp, gb + j3); int sd = __shfl(sp, gb + j3);
        float2 ra = *(const float2*)(h2h + (size_t)sa * HID + q * 4);
        float2 rb = *(const float2*)(h2h + (size_t)sb * HID + q * 4);
        float2 rc = *(const float2*)(h2h + (size_t)sc * HID + q * 4);
        float2 rd = *(const float2*)(h2h + (size_t)sd * HID + q * 4);
        float f0,f1,f2,f3;
        unp4(ra, f0,f1,f2,f3); a0=fmaf(wa,f0,a0); a1=fmaf(wa,f1,a1); a2=fmaf(wa,f2,a2); a3=fmaf(wa,f3,a3);
        unp4(rb, f0,f1,f2,f3); a0=fmaf(wb,f0,a0); a1=fmaf(wb,f1,a1); a2=fmaf(wb,f2,a2); a3=fmaf(wb,f3,a3);
        unp4(rc, f0,f1,f2,f3); a0=fmaf(wc,f0,a0); a1=fmaf(wc,f1,a1); a2=fmaf(wc,f2,a2); a3=fmaf(wc,f3,a3);
        unp4(rd, f0,f1,f2,f3); a0=fmaf(wd,f0,a0); a1=fmaf(wd,f1,a1); a2=fmaf(wd,f2,a2); a3=fmaf(wd,f3,a3);
      }
    };
    pass(w0r, s0r, 0); pass(w1r, s1r, 16); pass(w2r, s2r, 32); pass(w3r, s3r, 48);
    for (int e = e0 + 64; e < e1; ++e){
      int s = csr[e];
      float w = inv * expf(lrelu(als[s] + adn));
      float2 r = *(const float2*)(h2h + (size_t)s * HID + q * 4);
      float f0,f1,f2,f3; unp4(r, f0,f1,f2,f3);
      a0=fmaf(w,f0,a0); a1=fmaf(w,f1,a1); a2=fmaf(w,f2,a2); a3=fmaf(w,f3,a3);
    }

    float4 b4 = *(const float4*)(b2 + q * 4);
    __half2 p0 = __floats2half2_rn(elu_(a0 + b4.x), elu_(a1 + b4.y));
    __half2 p1 = __floats2half2_rn(elu_(a2 + b4.z), elu_(a3 + b4.w));
    float2 outv; ((__half2*)&outv)[0] = p0; ((__half2*)&outv)[1] = p1;
    *(float2*)(o_lds + nl * OSTRIDE + q * 4) = outv;
  }
  __syncthreads();

  // hW MFMA + fused scores (wave wv handles nodes n0b + wv*16 .. +15)
  const _Float16* obase = (const _Float16*)o_lds + (wv * 16 + (lane & 15)) * OSTRIDE + (lane >> 4) * 8;
  const f16x8* bbase = (const f16x8*)Bwh + lane;   // + (kt*4+ct)*64

  f32x4 acc[4];
#pragma unroll
  for (int ct = 0; ct < 4; ++ct) acc[ct] = (f32x4){0.f,0.f,0.f,0.f};
#pragma unroll
  for (int kt = 0; kt < 2; ++kt){
    f16x8 a = *(const f16x8*)(obase + kt * 32);
#pragma unroll
    for (int ct = 0; ct < 4; ++ct)
      acc[ct] = __builtin_amdgcn_mfma_f32_16x16x32_f16(a, bbase[(kt*4 + ct) * 64], acc[ct], 0, 0, 0);
  }
  int c4 = lane & 15, g4 = lane >> 4;
  float wv0 = w2s[c4], wv1 = w2s[16 + c4], wv2 = w2s[32 + c4], wv3 = w2s[48 + c4];
  float bias = b2s[0];
#pragma unroll
  for (int i = 0; i < 4; ++i){
    int n = n0b + wv * 16 + g4 * 4 + i;
    float v[16];
#pragma unroll
    for (int b = 0; b < 16; ++b){
      const float* twb = tws + b * 64;
      v[b] = fmaxf(acc[0][i] + twb[c4], 0.f)      * wv0
           + fmaxf(acc[1][i] + twb[16 + c4], 0.f) * wv1
           + fmaxf(acc[2][i] + twb[32 + c4], 0.f) * wv2
           + fmaxf(acc[3][i] + twb[48 + c4], 0.f) * wv3;
    }
    bool h3 = (lane & 8) != 0;
    float u[8];
#pragma unroll
    for (int jj = 0; jj < 8; ++jj){
      float keep = h3 ? v[jj+8] : v[jj];
      float send = h3 ? v[jj]   : v[jj+8];
      u[jj] = keep + __shfl_xor(send, 8);
    }
    bool h2b = (lane & 4) != 0;
    float p[4];
#pragma unroll
    for (int jj = 0; jj < 4; ++jj){
      float keep = h2b ? u[jj+4] : u[jj];
      float send = h2b ? u[jj]   : u[jj+4];
      p[jj] = keep + __shfl_xor(send, 4);
    }
    bool h1b = (lane & 2) != 0;
    float qq[2];
#pragma unroll
    for (int jj = 0; jj < 2; ++jj){
      float keep = h1b ? p[jj+2] : p[jj];
      float send = h1b ? p[jj]   : p[jj+2];
      qq[jj] = keep + __shfl_xor(send, 2);
    }
    bool h0 = (lane & 1) != 0;
    float keep = h0 ? qq[1] : qq[0];
    float send = h0 ? qq[0] : qq[1];
    float z = keep + __shfl_xor(send, 1);
    if (n < NN) out[(size_t)c4 * NN + n] = z + bias;
  }
}

extern "C" void kernel_launch(void* const* d_in, const int* in_sizes, int n_in,
                              void* d_out, int out_size, void* d_ws, size_t ws_size,
                              hipStream_t stream){
  const float* x    = (const float*)d_in[0];
  const int*   ei   = (const int*)  d_in[1];
  const float* task = (const float*)d_in[2];
  const float* W1   = (const float*)d_in[3];
  const float* as1  = (const float*)d_in[4];
  const float* ad1  = (const float*)d_in[5];
  const float* b1   = (const float*)d_in[6];
  const float* W2   = (const float*)d_in[7];
  const float* as2  = (const float*)d_in[8];
  const float* ad2  = (const float*)d_in[9];
  const float* b2   = (const float*)d_in[10];
  const float* teW1 = (const float*)d_in[11];
  const float* teb1 = (const float*)d_in[12];
  const float* teW2 = (const float*)d_in[13];
  const float* teb2 = (const float*)d_in[14];
  const float* clW1 = (const float*)d_in[15];
  const float* clb1 = (const float*)d_in[16];
  const float* clW2 = (const float*)d_in[17];
  const float* clb2 = (const float*)d_in[18];
  float* out = (float*)d_out;
  float* ws  = (float*)d_ws;

  // workspace layout (float-sized slots)
  __half* h1h  = (__half*)ws;                    // 12.8M halfs -> 6.4M floats
  float* als1  = ws + 6400000;                   // 200,000
  float* ald1  = als1 + 200000;                  // 200,000
  __half* h2h  = (__half*)(ald1 + 200000);       // 3.2M halfs -> 1.6M floats
  float* als2  = ald1 + 200000 + 1600000;        // 50,000
  float* ald2  = als2 + 50000;                   // 50,000
  float* tWb   = ald2 + 50000;                   // 1,024
  int*   rs    = (int*)(tWb + 1024);             // 50,001 (+pad)
  int*   csr   = rs + 50004;                     // 800,000
  int*   binCnt= csr + 800000;                   // 256
  __half* Bp   = (__half*)(binCnt + 256);        // 16,384 halfs (MFMA-ordered W2)
  __half* Bp1  = Bp + 16384;                     // 32,768 halfs (MFMA-ordered W1)
  __half* Bwh  = Bp1 + 32768;                    // 4,096 halfs (MFMA-ordered Wh)
  unsigned* pr = (unsigned*)(Bwh + 4096);        // 196*8192 packed pairs (6.4 MB)

  // weight prep + task encoder + binCnt zero (27 blocks)
  k_misc   <<<27, 256, 0, stream>>>(W2, W1, Bp, Bp1, Bwh,
                                    task, teW1, teb1, teW2, teb2, clW1, clb1, tWb, binCnt);
  // LDS-binned edge partition into regions + layer-1 GEMM (one launch)
  k_binGemm<<<200 + (NN + 63)/64, 256, 0, stream>>>(ei, binCnt, pr, x, Bp1,
                                                    as1, ad1, h1h, als1, ald1);
  // rs + csr from regions
  k_rsplace<<<NBKT, 256, 0, stream>>>(binCnt, pr, rs, csr);
  // layer 1 aggregate + layer-2 GEMM + alpha2 (fused; 3125*16 == NN)
  k_agg1f2 <<<3125, 256, 0, stream>>>(rs, csr, h1h, als1, ald1, b1,
                                      Bp, as2, ad2, h2h, als2, ald2);
  // layer 2 aggregate + hW MFMA + scores (fused)
  k_agg2f  <<<(NN + 63)/64, 256, 0, stream>>>(rs, csr, h2h, als2, ald2, b2,
                                              Bwh, tWb, clW2, clb2, out);
}